// Round 17
// baseline (253.824 us; speedup 1.0000x reference)
//
#include <hip/hip_runtime.h>
#include <hip/hip_bf16.h>

#define NN 100000
#define EE 3200000

#define NBKT 196       // coarse buckets: d>>9, 196*512 >= NN
#define NBH  391       // bhist/bscatter blocks: 391*8192 >= EE
#define NTOT (NBKT*NBH)   // 76636

typedef short bf16x8 __attribute__((ext_vector_type(8)));
typedef float f32x16 __attribute__((ext_vector_type(16)));

// ---- fast-path ws layout (ints), ~56.2 MB ----
#define WS_SD2F  0            // int2[EE]
#define WS_TMP2  6400000      // u32[EE] (packed src|dlow)
#define WS_OFFF  12800000     // int[NN+1]
#define WS_H     12900032     // int[NTOT]
#define WS_PARTF 13053440     // int[128]
#define WS_H4F   13053568     // float[4N]
#define WS_OUT4F 13453568     // float[4N]
#define WS_ZF    13853568     // float[2N]
#define WS_PREP  14053568     // 2560 u32 prepacked A-fragments
#define NEED_FAST ((size_t)14056384 * 4)

// ---- fallback (round-6) ws layout (ints), ~30.4 MB ----
#define FB_SD2  0
#define FB_OFF  6400000
#define FB_CNT  6500032
#define FB_PART 6600032
#define FB_H4   6600192
#define FB_OUT4 7000192
#define FB_Z    7400192
#define FB_TMP  6600192      // u8[EE] overlay of h4/out4
#define FB_PREP 7600192

// exact round-to-nearest-even f32->bf16 (finite inputs)
static __device__ __forceinline__ unsigned short f2bf_fast(float f) {
    unsigned u = __builtin_bit_cast(unsigned, f);
    return (unsigned short)((u + 0x7fffu + ((u >> 16) & 1u)) >> 16);
}

// packed f32x2 -> bf16x2 (RNE), single instruction
static __device__ __forceinline__ unsigned cvtpk(float a, float b) {
    unsigned r;
    asm("v_cvt_pk_bf16_f32 %0, %1, %2" : "=v"(r) : "v"(a), "v"(b));
    return r;
}
// swap a.hi-lanes with b.lo-lanes: a' = [a.lo | b.lo], b' = [a.hi | b.hi]
static __device__ __forceinline__ void pl32swap(unsigned &a, unsigned &b) {
    asm("v_permlane32_swap_b32 %0, %1" : "+v"(a), "+v"(b));
}

// fast zero fill: one int4 per thread (fallback path only)
__global__ __launch_bounds__(256) void zero_kernel(int4* __restrict__ p, int n4)
{
    int i = blockIdx.x * 256 + threadIdx.x;
    if (i < n4) p[i] = make_int4(0, 0, 0, 0);
}

// ================= weight prepack (fallback path standalone) =================
__global__ __launch_bounds__(128) void wprep_kernel(
    const float* __restrict__ encW1, const float* __restrict__ encb1,
    const float* __restrict__ encW2,
    const float* __restrict__ muW,   const float* __restrict__ vW,
    const float* __restrict__ decW1, const float* __restrict__ decb1,
    const float* __restrict__ decW2,
    const float* __restrict__ decW3, unsigned int* __restrict__ prep)
{
    int t = threadIdx.x;
    int v = t >> 6, l = t & 63;
    int j = l & 31, h = l >> 5;
    const float* W1 = v ? decW1 : encW1;
    const float* b1 = v ? decb1 : encb1;
    const float* W2 = v ? decW2 : encW2;
    int K1 = v ? 4 : 8;
    unsigned short frag[5][8];
#pragma unroll
    for (int i = 0; i < 8; ++i) {
        unsigned short f0;
        if (h == 0) f0 = (i < K1) ? f2bf_fast(W1[i * 32 + j]) : (unsigned short)0;
        else        f0 = (i == 0) ? f2bf_fast(b1[j]) : (unsigned short)0;
        frag[0][i] = f0;
        int k0 = 8 * h + i, k1 = 16 + 8 * h + i;
        frag[1][i] = f2bf_fast(W2[k0 * 32 + j]);
        frag[2][i] = f2bf_fast(W2[k1 * 32 + j]);
        unsigned short w0 = 0, w1 = 0;
        if (j < 4) {
            if (v == 0) {
                w0 = (j < 2) ? f2bf_fast(muW[k0 * 2 + j]) : f2bf_fast(vW[k0 * 2 + (j - 2)]);
                w1 = (j < 2) ? f2bf_fast(muW[k1 * 2 + j]) : f2bf_fast(vW[k1 * 2 + (j - 2)]);
            } else {
                w0 = f2bf_fast(decW3[k0 * 4 + j]);
                w1 = f2bf_fast(decW3[k1 * 4 + j]);
            }
        }
        frag[3][i] = w0; frag[4][i] = w1;
    }
    uint4* fp = (uint4*)prep;
#pragma unroll
    for (int f = 0; f < 5; ++f) {
        uint4 wds;
        wds.x = (unsigned)frag[f][0] | ((unsigned)frag[f][1] << 16);
        wds.y = (unsigned)frag[f][2] | ((unsigned)frag[f][3] << 16);
        wds.z = (unsigned)frag[f][4] | ((unsigned)frag[f][5] << 16);
        wds.w = (unsigned)frag[f][6] | ((unsigned)frag[f][7] << 16);
        fp[(v * 5 + f) * 64 + l] = wds;
    }
}

// ================= fast-path CSR build (no global atomics) =================

// bhist + h4/out4 zeroing + (block 0) weight prepack, fused.
__global__ __launch_bounds__(256) void bhist_fused(
    const int* __restrict__ ei, int* __restrict__ H,
    int4* __restrict__ zbuf,                      // h4+out4, 200000 int4
    const float* __restrict__ encW1, const float* __restrict__ encb1,
    const float* __restrict__ encW2,
    const float* __restrict__ muW,   const float* __restrict__ vW,
    const float* __restrict__ decW1, const float* __restrict__ decb1,
    const float* __restrict__ decW2,
    const float* __restrict__ decW3, unsigned int* __restrict__ prep)
{
    __shared__ int hist[NBKT];
    int t = threadIdx.x;

    // zero slice: 512 int4 per block (391*512 = 200192 >= 200000)
    {
        int zi = blockIdx.x * 512 + t;
        if (zi < 200000) zbuf[zi] = make_int4(0, 0, 0, 0);
        zi += 256;
        if (zi < 200000) zbuf[zi] = make_int4(0, 0, 0, 0);
    }

    if (t < NBKT) hist[t] = 0;
    __syncthreads();
    int base = blockIdx.x * 8192;
#pragma unroll
    for (int k = 0; k < 32; ++k) {
        int e = base + k * 256 + t;
        if (e < EE) atomicAdd(&hist[ei[EE + e] >> 9], 1);
    }
    __syncthreads();
    if (t < NBKT) H[t * NBH + blockIdx.x] = hist[t];

    // weight prepack tail (block 0, threads 0-127; no barriers below)
    if (blockIdx.x == 0 && t < 128) {
        int v = t >> 6, l = t & 63;
        int j = l & 31, h = l >> 5;
        const float* W1 = v ? decW1 : encW1;
        const float* b1 = v ? decb1 : encb1;
        const float* W2 = v ? decW2 : encW2;
        int K1 = v ? 4 : 8;
        unsigned short frag[5][8];
#pragma unroll
        for (int i = 0; i < 8; ++i) {
            unsigned short f0;
            if (h == 0) f0 = (i < K1) ? f2bf_fast(W1[i * 32 + j]) : (unsigned short)0;
            else        f0 = (i == 0) ? f2bf_fast(b1[j]) : (unsigned short)0;
            frag[0][i] = f0;
            int k0 = 8 * h + i, k1 = 16 + 8 * h + i;
            frag[1][i] = f2bf_fast(W2[k0 * 32 + j]);
            frag[2][i] = f2bf_fast(W2[k1 * 32 + j]);
            unsigned short w0 = 0, w1 = 0;
            if (j < 4) {
                if (v == 0) {
                    w0 = (j < 2) ? f2bf_fast(muW[k0 * 2 + j]) : f2bf_fast(vW[k0 * 2 + (j - 2)]);
                    w1 = (j < 2) ? f2bf_fast(muW[k1 * 2 + j]) : f2bf_fast(vW[k1 * 2 + (j - 2)]);
                } else {
                    w0 = f2bf_fast(decW3[k0 * 4 + j]);
                    w1 = f2bf_fast(decW3[k1 * 4 + j]);
                }
            }
            frag[3][i] = w0; frag[4][i] = w1;
        }
        uint4* fp = (uint4*)prep;
#pragma unroll
        for (int f = 0; f < 5; ++f) {
            uint4 wds;
            wds.x = (unsigned)frag[f][0] | ((unsigned)frag[f][1] << 16);
            wds.y = (unsigned)frag[f][2] | ((unsigned)frag[f][3] << 16);
            wds.z = (unsigned)frag[f][4] | ((unsigned)frag[f][5] << 16);
            wds.w = (unsigned)frag[f][6] | ((unsigned)frag[f][7] << 16);
            fp[(v * 5 + f) * 64 + l] = wds;
        }
    }
}

// single-block exclusive scan over H[NTOT] (in place), 1024 threads x 76 elems
__global__ __launch_bounds__(1024) void scan_all(int* __restrict__ H, int n)
{
    const int CH = 76;   // 76*1024 = 77824 >= NTOT
    __shared__ int ls[1024];
    int t = threadIdx.x;
    int lo = t * CH;
    int hi = lo + CH; if (hi > n) hi = n;
    int s = 0;
    for (int i = lo; i < hi; ++i) s += H[i];
    ls[t] = s;
    __syncthreads();
    for (int d = 1; d < 1024; d <<= 1) {
        int u = (t >= d) ? ls[t - d] : 0;
        __syncthreads();
        ls[t] += u;
        __syncthreads();
    }
    int run = ls[t] - s;   // exclusive prefix of this chunk
    for (int i = lo; i < hi; ++i) { int v = H[i]; H[i] = run; run += v; }
}

// packed tmp2: bits 0-16 = src (<2^17), bits 17-25 = dst & 511
__global__ __launch_bounds__(256) void bscatter(
    const int* __restrict__ ei, const int* __restrict__ S, unsigned* __restrict__ tmp2)
{
    __shared__ int cur[NBKT];
    int t = threadIdx.x;
    if (t < NBKT) cur[t] = S[t * NBH + blockIdx.x];
    __syncthreads();
    int base = blockIdx.x * 8192;
#pragma unroll
    for (int k = 0; k < 32; ++k) {
        int e = base + k * 256 + t;
        if (e < EE) {
            int s = ei[e], d = ei[EE + e];
            int p = atomicAdd(&cur[d >> 9], 1);
            tmp2[p] = ((unsigned)(d & 511) << 17) | (unsigned)s;
        }
    }
}

__global__ __launch_bounds__(1024) void bsort(
    const unsigned* __restrict__ tmp2, const int* __restrict__ S,
    int2* __restrict__ sd2, int* __restrict__ off)
{
    int b = blockIdx.x, t = threadIdx.x;
    int bstart = S[b * NBH];
    int bend = (b < NBKT - 1) ? S[(b + 1) * NBH] : EE;
    __shared__ int hist[512], sa[512], sbuf[512];
    if (t < 512) hist[t] = 0;
    __syncthreads();
    for (int e = bstart + t; e < bend; e += 1024)
        atomicAdd(&hist[(tmp2[e] >> 17) & 511], 1);
    __syncthreads();
    int v = 0;
    if (t < 512) { v = hist[t]; sa[t] = v; }
    __syncthreads();
    int *pa = sa, *pb = sbuf;
    for (int d = 1; d < 512; d <<= 1) {
        if (t < 512) pb[t] = pa[t] + ((t >= d) ? pa[t - d] : 0);
        __syncthreads();
        int* tp = pa; pa = pb; pb = tp;
    }
    if (t < 512) {
        int base = bstart + pa[t] - v;   // exclusive
        int n = b * 512 + t;
        if (n < NN) off[n] = base;
        hist[t] = base;                  // cursor
    }
    if (b == 0 && t == 0) off[NN] = EE;
    __syncthreads();
    for (int e = bstart + t; e < bend; e += 1024) {
        unsigned ed = tmp2[e];
        int bin = (int)((ed >> 17) & 511);
        int p = atomicAdd(&hist[bin], 1);
        sd2[p] = make_int2((int)(ed & 0x1FFFFu), (b << 9) | bin);
    }
}

// ================= fallback CSR build (round-6, proven) =================

__global__ __launch_bounds__(256) void rank_kernel(
    const int* __restrict__ ei, int* __restrict__ cnt, unsigned char* __restrict__ tmp)
{
    int e = blockIdx.x * 256 + threadIdx.x;
    int d = ei[EE + e];
    tmp[e] = (unsigned char)atomicAdd(&cnt[d], 1);
}

__global__ __launch_bounds__(256) void partial_kernel(
    const int* __restrict__ cnt, int* __restrict__ partials)
{
    int i0 = blockIdx.x * 1024 + threadIdx.x * 4;
    int s = 0;
    if (i0 + 3 < NN) {
        int4 v = *(const int4*)(cnt + i0);
        s = v.x + v.y + v.z + v.w;
    } else {
        for (int i = i0; i < NN; ++i) s += cnt[i];
    }
#pragma unroll
    for (int d = 1; d < 64; d <<= 1) s += __shfl_xor(s, d);
    __shared__ int ws_[4];
    if ((threadIdx.x & 63) == 0) ws_[threadIdx.x >> 6] = s;
    __syncthreads();
    if (threadIdx.x == 0) partials[blockIdx.x] = ws_[0] + ws_[1] + ws_[2] + ws_[3];
}

__global__ __launch_bounds__(128) void scan_partials(
    int* __restrict__ partials, int* __restrict__ off)
{
    __shared__ int ls[128];
    int t = threadIdx.x;
    int v = (t < 98) ? partials[t] : 0;
    ls[t] = v;
    __syncthreads();
#pragma unroll
    for (int d = 1; d < 128; d <<= 1) {
        int u = (t >= d) ? ls[t - d] : 0;
        __syncthreads();
        ls[t] += u;
        __syncthreads();
    }
    if (t < 98) partials[t] = ls[t] - v;
    if (t == 127) off[NN] = ls[127];
}

__global__ __launch_bounds__(256) void final_scan(
    const int* __restrict__ cnt, const int* __restrict__ partials, int* __restrict__ off)
{
    int t = threadIdx.x;
    int i0 = blockIdx.x * 1024 + t * 4;
    int4 v = {0, 0, 0, 0};
    if (i0 + 3 < NN) {
        v = *(const int4*)(cnt + i0);
    } else {
        int tv[4] = {0, 0, 0, 0};
        for (int k = 0; k < 4 && i0 + k < NN; ++k) tv[k] = cnt[i0 + k];
        v.x = tv[0]; v.y = tv[1]; v.z = tv[2]; v.w = tv[3];
    }
    int s = v.x + v.y + v.z + v.w;
    __shared__ int ls[256];
    ls[t] = s;
    __syncthreads();
#pragma unroll
    for (int d = 1; d < 256; d <<= 1) {
        int u = (t >= d) ? ls[t - d] : 0;
        __syncthreads();
        ls[t] += u;
        __syncthreads();
    }
    int base = partials[blockIdx.x] + ls[t] - s;
    int4 o;
    o.x = base; o.y = base + v.x; o.z = o.y + v.y; o.w = o.z + v.z;
    if (i0 + 3 < NN) {
        *(int4*)(off + i0) = o;
    } else {
        int oo[4] = {o.x, o.y, o.z, o.w};
        for (int k = 0; k < 4 && i0 + k < NN; ++k) off[i0 + k] = oo[k];
    }
}

__global__ __launch_bounds__(256) void place_kernel(
    const int* __restrict__ ei, const int* __restrict__ off,
    const unsigned char* __restrict__ tmp, int2* __restrict__ sd2)
{
    int e = blockIdx.x * 256 + threadIdx.x;
    int s = ei[e], d = ei[EE + e];
    int p = off[d] + (int)tmp[e];
    sd2[p] = make_int2(s, d);
}

// ================= edge MLP: swapped-operand MFMA, in-register transposes =================
// 4 waves/block, each wave processes 128 CSR-consecutive edges (2 x 64-edge pairs).
// __launch_bounds__(256,4): VGPR cap 128 so f32x16 temps stay in VGPRs (no AGPR shuffle).
__global__ __launch_bounds__(256, 4) void edge_mfma(
    const float* __restrict__ feat, int fdim,
    const uint4* __restrict__ wfrag, const float* __restrict__ b2,
    const int2* __restrict__ sd2,
    float* __restrict__ agg4)
{
    __shared__ int   sd[4][128];
    __shared__ float sm4[4][128][5];
    int t = threadIdx.x;
    int w = t >> 6, l = t & 63;
    int h = l >> 5;
    int ebase = (blockIdx.x * 4 + w) * 128;

    // prepacked A fragments (wave-invariant)
    bf16x8 A1  = __builtin_bit_cast(bf16x8, wfrag[l]);
    bf16x8 A2a = __builtin_bit_cast(bf16x8, wfrag[64 + l]);
    bf16x8 A2b = __builtin_bit_cast(bf16x8, wfrag[128 + l]);
    bf16x8 A3a = __builtin_bit_cast(bf16x8, wfrag[192 + l]);
    bf16x8 A3b = __builtin_bit_cast(bf16x8, wfrag[256 + l]);

    // layer-2 bias as MFMA C-in: reg r -> b2[(r&3)+8*(r>>2)+4h]
    f32x16 cb;
    {
        float4 q0 = *(const float4*)(b2 + 4 * h);
        float4 q1 = *(const float4*)(b2 + 8 + 4 * h);
        float4 q2 = *(const float4*)(b2 + 16 + 4 * h);
        float4 q3 = *(const float4*)(b2 + 24 + 4 * h);
        cb[0] = q0.x; cb[1] = q0.y; cb[2] = q0.z; cb[3] = q0.w;
        cb[4] = q1.x; cb[5] = q1.y; cb[6] = q1.z; cb[7] = q1.w;
        cb[8] = q2.x; cb[9] = q2.y; cb[10] = q2.z; cb[11] = q2.w;
        cb[12] = q3.x; cb[13] = q3.y; cb[14] = q3.z; cb[15] = q3.w;
    }

    f32x16 czero = {0.f,0.f,0.f,0.f,0.f,0.f,0.f,0.f,0.f,0.f,0.f,0.f,0.f,0.f,0.f,0.f};

    auto tile = [&](const f32x16& D1, float& o0, float& o1, float& o2, float& o3) {
        unsigned c0 = cvtpk(fmaxf(D1[0], 0.f),  fmaxf(D1[1], 0.f));
        unsigned c1 = cvtpk(fmaxf(D1[2], 0.f),  fmaxf(D1[3], 0.f));
        unsigned c2 = cvtpk(fmaxf(D1[4], 0.f),  fmaxf(D1[5], 0.f));
        unsigned c3 = cvtpk(fmaxf(D1[6], 0.f),  fmaxf(D1[7], 0.f));
        unsigned c4 = cvtpk(fmaxf(D1[8], 0.f),  fmaxf(D1[9], 0.f));
        unsigned c5 = cvtpk(fmaxf(D1[10], 0.f), fmaxf(D1[11], 0.f));
        unsigned c6 = cvtpk(fmaxf(D1[12], 0.f), fmaxf(D1[13], 0.f));
        unsigned c7 = cvtpk(fmaxf(D1[14], 0.f), fmaxf(D1[15], 0.f));
        pl32swap(c0, c2); pl32swap(c1, c3); pl32swap(c4, c6); pl32swap(c5, c7);
        bf16x8 B2a = __builtin_bit_cast(bf16x8, make_uint4(c0, c1, c2, c3));
        bf16x8 B2b = __builtin_bit_cast(bf16x8, make_uint4(c4, c5, c6, c7));
        f32x16 acc = cb;
        acc = __builtin_amdgcn_mfma_f32_32x32x16_bf16(A2a, B2a, acc, 0, 0, 0);
        acc = __builtin_amdgcn_mfma_f32_32x32x16_bf16(A2b, B2b, acc, 0, 0, 0);
        unsigned d0 = cvtpk(fmaxf(acc[0], 0.f),  fmaxf(acc[1], 0.f));
        unsigned d1 = cvtpk(fmaxf(acc[2], 0.f),  fmaxf(acc[3], 0.f));
        unsigned d2 = cvtpk(fmaxf(acc[4], 0.f),  fmaxf(acc[5], 0.f));
        unsigned d3 = cvtpk(fmaxf(acc[6], 0.f),  fmaxf(acc[7], 0.f));
        unsigned d4 = cvtpk(fmaxf(acc[8], 0.f),  fmaxf(acc[9], 0.f));
        unsigned d5 = cvtpk(fmaxf(acc[10], 0.f), fmaxf(acc[11], 0.f));
        unsigned d6 = cvtpk(fmaxf(acc[12], 0.f), fmaxf(acc[13], 0.f));
        unsigned d7 = cvtpk(fmaxf(acc[14], 0.f), fmaxf(acc[15], 0.f));
        pl32swap(d0, d2); pl32swap(d1, d3); pl32swap(d4, d6); pl32swap(d5, d7);
        bf16x8 B3a = __builtin_bit_cast(bf16x8, make_uint4(d0, d1, d2, d3));
        bf16x8 B3b = __builtin_bit_cast(bf16x8, make_uint4(d4, d5, d6, d7));
        f32x16 D3 = czero;
        D3 = __builtin_amdgcn_mfma_f32_32x32x16_bf16(A3a, B3a, D3, 0, 0, 0);
        D3 = __builtin_amdgcn_mfma_f32_32x32x16_bf16(A3b, B3b, D3, 0, 0, 0);
        o0 = D3[0]; o1 = D3[1]; o2 = D3[2]; o3 = D3[3];
    };

#pragma unroll
    for (int p = 0; p < 2; ++p) {
        int eb = ebase + 64 * p;
        int2 me = sd2[eb + l];
        sd[w][64 * p + l] = me.y;

        unsigned F0 = 0, F1 = 0, F2 = 0, F3 = 0;
        if (fdim == 4) {
            float4 xd = *(const float4*)(feat + 4 * me.y);
            float4 xs = *(const float4*)(feat + 4 * me.x);
            F0 = cvtpk(xd.x, xd.y);
            F1 = cvtpk(xd.z, xd.w);
            F2 = cvtpk(xs.x - xd.x, xs.y - xd.y);
            F3 = cvtpk(xs.z - xd.z, xs.w - xd.w);
        } else {
            float2 zd = *(const float2*)(feat + 2 * me.y);
            float2 zs = *(const float2*)(feat + 2 * me.x);
            F0 = cvtpk(zd.x, zd.y);
            F1 = cvtpk(zs.x - zd.x, zs.y - zd.y);
        }
        unsigned G0 = 0x00003F80u, G1 = 0, G2 = 0, G3 = 0;
        pl32swap(F0, G0);
        pl32swap(F1, G1);
        pl32swap(F2, G2);
        pl32swap(F3, G3);
        bf16x8 B1a = __builtin_bit_cast(bf16x8, make_uint4(F0, F1, F2, F3));
        bf16x8 B1b = __builtin_bit_cast(bf16x8, make_uint4(G0, G1, G2, G3));

        float o0, o1, o2, o3;
        f32x16 D1a = __builtin_amdgcn_mfma_f32_32x32x16_bf16(A1, B1a, czero, 0, 0, 0);
        tile(D1a, o0, o1, o2, o3);
        if (h == 0) {
            sm4[w][64 * p + l][0] = o0; sm4[w][64 * p + l][1] = o1;
            sm4[w][64 * p + l][2] = o2; sm4[w][64 * p + l][3] = o3;
        }
        f32x16 D1b = __builtin_amdgcn_mfma_f32_32x32x16_bf16(A1, B1b, czero, 0, 0, 0);
        tile(D1b, o0, o1, o2, o3);
        if (h == 0) {
            sm4[w][64 * p + 32 + l][0] = o0; sm4[w][64 * p + 32 + l][1] = o1;
            sm4[w][64 * p + 32 + l][2] = o2; sm4[w][64 * p + 32 + l][3] = o3;
        }
    }

    // wave-local LDS: intra-wave DS ordering; stop compiler reordering
    asm volatile("" ::: "memory");

    // flush: lane l handles channel c = l&3 over edges [8*seg, 8*seg+8)
    int c = l & 3, e0 = (l >> 2) * 8;
    int cur = sd[w][e0];
    float acc4 = 0.f;
#pragma unroll
    for (int k = 0; k < 8; ++k) {
        int dr = sd[w][e0 + k];
        if (dr != cur) { atomicAdd(&agg4[cur * 4 + c], acc4); acc4 = 0.f; cur = dr; }
        acc4 += sm4[w][e0 + k][c];
    }
    atomicAdd(&agg4[cur * 4 + c], acc4);
}

__global__ __launch_bounds__(256) void node_kernel(
    const float* __restrict__ h4, const int* __restrict__ off,
    const float* __restrict__ eps,
    const float* __restrict__ mub, const float* __restrict__ vb,
    float* __restrict__ z, float* __restrict__ out)
{
    int n = blockIdx.x * 256 + threadIdx.x;
    if (n >= NN) return;
    float inv = 1.f / fmaxf((float)(off[n + 1] - off[n]), 1.f);
    float4 a = *(const float4*)(h4 + 4 * n);
    float mu0 = a.x * inv + mub[0], mu1 = a.y * inv + mub[1];
    float lv0 = a.z * inv + vb[0],  lv1 = a.w * inv + vb[1];
    out[4 * NN + 2 * n]     = mu0;
    out[4 * NN + 2 * n + 1] = mu1;
    out[6 * NN + 2 * n]     = lv0;
    out[6 * NN + 2 * n + 1] = lv1;
    float2 zz;
    zz.x = mu0 + eps[2 * n]     * expf(0.5f * lv0);
    zz.y = mu1 + eps[2 * n + 1] * expf(0.5f * lv1);
    *(float2*)(z + 2 * n) = zz;
}

__global__ __launch_bounds__(256) void final_kernel(
    const float* __restrict__ o4, const int* __restrict__ off,
    const float* __restrict__ b3, float* __restrict__ out)
{
    int n = blockIdx.x * 256 + threadIdx.x;
    if (n >= NN) return;
    float inv = 1.f / fmaxf((float)(off[n + 1] - off[n]), 1.f);
    float4 a = *(const float4*)(o4 + 4 * n);
    float4 r;
    r.x = a.x * inv + b3[0]; r.y = a.y * inv + b3[1];
    r.z = a.z * inv + b3[2]; r.w = a.w * inv + b3[3];
    *(float4*)(out + 4 * n) = r;
}

extern "C" void kernel_launch(void* const* d_in, const int* in_sizes, int n_in,
                              void* d_out, int out_size, void* d_ws, size_t ws_size,
                              hipStream_t stream)
{
    const float* x     = (const float*)d_in[0];
    const int*   ei    = (const int*)d_in[1];
    const float* eps   = (const float*)d_in[2];
    const float* encW1 = (const float*)d_in[3];
    const float* encb1 = (const float*)d_in[4];
    const float* encW2 = (const float*)d_in[5];
    const float* encb2 = (const float*)d_in[6];
    const float* muW   = (const float*)d_in[7];
    const float* mub   = (const float*)d_in[8];
    const float* vW    = (const float*)d_in[9];
    const float* vb    = (const float*)d_in[10];
    const float* decW1 = (const float*)d_in[11];
    const float* decb1 = (const float*)d_in[12];
    const float* decW2 = (const float*)d_in[13];
    const float* decb2 = (const float*)d_in[14];
    const float* decW3 = (const float*)d_in[15];
    const float* decb3 = (const float*)d_in[16];

    int*   wsI = (int*)d_ws;
    float* wsF = (float*)d_ws;
    dim3 blk(256);
    dim3 egrid(6250);                 // 6250 * 4 waves * 128 edges = EE
    dim3 ngrid((NN + 255) / 256);

    int2* sd2; int* off; float* h4; float* out4; float* z; unsigned int* prep;

    if (ws_size >= NEED_FAST) {
        // -------- fast path: LDS-privatized two-level bucket sort (8 dispatches) --------
        sd2  = (int2*)(wsI + WS_SD2F);
        unsigned* tmp2 = (unsigned*)(wsI + WS_TMP2);
        off  = wsI + WS_OFFF;
        int* H    = wsI + WS_H;
        h4   = wsF + WS_H4F;
        out4 = wsF + WS_OUT4F;
        z    = wsF + WS_ZF;
        prep = (unsigned int*)(wsI + WS_PREP);

        bhist_fused<<<dim3(NBH), blk, 0, stream>>>(
            ei, H, (int4*)(wsF + WS_H4F),
            encW1, encb1, encW2, muW, vW,
            decW1, decb1, decW2, decW3, prep);
        scan_all<<<dim3(1), dim3(1024), 0, stream>>>(H, NTOT);
        bscatter<<<dim3(NBH), blk, 0, stream>>>(ei, H, tmp2);
        bsort<<<dim3(NBKT), dim3(1024), 0, stream>>>(tmp2, H, sd2, off);
    } else {
        // -------- fallback: round-6 build (global-atomic rank) --------
        sd2  = (int2*)(wsI + FB_SD2);
        off  = wsI + FB_OFF;
        int* cnt  = wsI + FB_CNT;
        int* part = wsI + FB_PART;
        unsigned char* tmp = (unsigned char*)(wsI + FB_TMP);
        h4   = wsF + FB_H4;
        out4 = wsF + FB_OUT4;
        z    = wsF + FB_Z;
        prep = (unsigned int*)(wsI + FB_PREP);

        zero_kernel<<<dim3(98), blk, 0, stream>>>((int4*)(wsI + FB_CNT), 25000);
        wprep_kernel<<<dim3(1), dim3(128), 0, stream>>>(
            encW1, encb1, encW2, muW, vW,
            decW1, decb1, decW2, decW3, prep);
        rank_kernel<<<dim3(12500), blk, 0, stream>>>(ei, cnt, tmp);
        partial_kernel<<<dim3(98), blk, 0, stream>>>(cnt, part);
        scan_partials<<<dim3(1), dim3(128), 0, stream>>>(part, off);
        final_scan<<<dim3(98), blk, 0, stream>>>(cnt, part, off);
        place_kernel<<<dim3(12500), blk, 0, stream>>>(ei, off, tmp, sd2);
        zero_kernel<<<dim3(782), blk, 0, stream>>>((int4*)(wsF + FB_H4), 200000);
    }

    const uint4* wf = (const uint4*)prep;

    edge_mfma<<<egrid, blk, 0, stream>>>(x, 4, wf, encb2, sd2, h4);
    node_kernel<<<ngrid, blk, 0, stream>>>(h4, off, eps, mub, vb, z, (float*)d_out);
    edge_mfma<<<egrid, blk, 0, stream>>>(z, 2, wf + 5 * 64, decb2, sd2, out4);
    final_kernel<<<ngrid, blk, 0, stream>>>(out4, off, decb3, (float*)d_out);
}

// Round 20
// 143.061 us; speedup vs baseline: 1.7742x; 1.7742x over previous
//
#include <hip/hip_runtime.h>
#include <hip/hip_bf16.h>

#define NN 100000
#define EE 3200000

#define NBKT 196       // coarse buckets: d>>9, 196*512 >= NN
#define NBH  391       // bhist/bscatter blocks: 391*8192 >= EE
#define NTOT (NBKT*NBH)   // 76636
#define NSB  38        // scan blocks: 38*2048 >= NTOT

typedef short bf16x8 __attribute__((ext_vector_type(8)));
typedef float f32x16 __attribute__((ext_vector_type(16)));

// ---- fast-path ws layout (ints), ~56.2 MB ----
#define WS_SD2F  0            // int2[EE]
#define WS_TMP2  6400000      // u32[EE] (packed src|dlow)
#define WS_OFFF  12800000     // int[NN+1]
#define WS_H     12900032     // int[NTOT]
#define WS_PARTF 13053440     // int[128]
#define WS_H4F   13053568     // float[4N]
#define WS_OUT4F 13453568     // float[4N]
#define WS_ZF    13853568     // float[2N]
#define WS_PREP  14053568     // 2560 u32 prepacked A-fragments
#define NEED_FAST ((size_t)14056384 * 4)

// ---- fallback (round-6) ws layout (ints), ~30.4 MB ----
#define FB_SD2  0
#define FB_OFF  6400000
#define FB_CNT  6500032
#define FB_PART 6600032
#define FB_H4   6600192
#define FB_OUT4 7000192
#define FB_Z    7400192
#define FB_TMP  6600192      // u8[EE] overlay of h4/out4
#define FB_PREP 7600192

// exact round-to-nearest-even f32->bf16 (finite inputs)
static __device__ __forceinline__ unsigned short f2bf_fast(float f) {
    unsigned u = __builtin_bit_cast(unsigned, f);
    return (unsigned short)((u + 0x7fffu + ((u >> 16) & 1u)) >> 16);
}

// packed f32x2 -> bf16x2 (RNE), single instruction
static __device__ __forceinline__ unsigned cvtpk(float a, float b) {
    unsigned r;
    asm("v_cvt_pk_bf16_f32 %0, %1, %2" : "=v"(r) : "v"(a), "v"(b));
    return r;
}
// swap a.hi-lanes with b.lo-lanes: a' = [a.lo | b.lo], b' = [a.hi | b.hi]
static __device__ __forceinline__ void pl32swap(unsigned &a, unsigned &b) {
    asm("v_permlane32_swap_b32 %0, %1" : "+v"(a), "+v"(b));
}

// fast zero fill: one int4 per thread (fallback path only)
__global__ __launch_bounds__(256) void zero_kernel(int4* __restrict__ p, int n4)
{
    int i = blockIdx.x * 256 + threadIdx.x;
    if (i < n4) p[i] = make_int4(0, 0, 0, 0);
}

// ================= weight prepack (fallback path standalone) =================
__global__ __launch_bounds__(128) void wprep_kernel(
    const float* __restrict__ encW1, const float* __restrict__ encb1,
    const float* __restrict__ encW2,
    const float* __restrict__ muW,   const float* __restrict__ vW,
    const float* __restrict__ decW1, const float* __restrict__ decb1,
    const float* __restrict__ decW2,
    const float* __restrict__ decW3, unsigned int* __restrict__ prep)
{
    int t = threadIdx.x;
    int v = t >> 6, l = t & 63;
    int j = l & 31, h = l >> 5;
    const float* W1 = v ? decW1 : encW1;
    const float* b1 = v ? decb1 : encb1;
    const float* W2 = v ? decW2 : encW2;
    int K1 = v ? 4 : 8;
    unsigned short frag[5][8];
#pragma unroll
    for (int i = 0; i < 8; ++i) {
        unsigned short f0;
        if (h == 0) f0 = (i < K1) ? f2bf_fast(W1[i * 32 + j]) : (unsigned short)0;
        else        f0 = (i == 0) ? f2bf_fast(b1[j]) : (unsigned short)0;
        frag[0][i] = f0;
        int k0 = 8 * h + i, k1 = 16 + 8 * h + i;
        frag[1][i] = f2bf_fast(W2[k0 * 32 + j]);
        frag[2][i] = f2bf_fast(W2[k1 * 32 + j]);
        unsigned short w0 = 0, w1 = 0;
        if (j < 4) {
            if (v == 0) {
                w0 = (j < 2) ? f2bf_fast(muW[k0 * 2 + j]) : f2bf_fast(vW[k0 * 2 + (j - 2)]);
                w1 = (j < 2) ? f2bf_fast(muW[k1 * 2 + j]) : f2bf_fast(vW[k1 * 2 + (j - 2)]);
            } else {
                w0 = f2bf_fast(decW3[k0 * 4 + j]);
                w1 = f2bf_fast(decW3[k1 * 4 + j]);
            }
        }
        frag[3][i] = w0; frag[4][i] = w1;
    }
    uint4* fp = (uint4*)prep;
#pragma unroll
    for (int f = 0; f < 5; ++f) {
        uint4 wds;
        wds.x = (unsigned)frag[f][0] | ((unsigned)frag[f][1] << 16);
        wds.y = (unsigned)frag[f][2] | ((unsigned)frag[f][3] << 16);
        wds.z = (unsigned)frag[f][4] | ((unsigned)frag[f][5] << 16);
        wds.w = (unsigned)frag[f][6] | ((unsigned)frag[f][7] << 16);
        fp[(v * 5 + f) * 64 + l] = wds;
    }
}

// ================= fast-path CSR build (no global atomics) =================

// bhist + h4/out4 zeroing + (block 0) weight prepack, fused.
__global__ __launch_bounds__(256) void bhist_fused(
    const int* __restrict__ ei, int* __restrict__ H,
    int4* __restrict__ zbuf,                      // h4+out4, 200000 int4
    const float* __restrict__ encW1, const float* __restrict__ encb1,
    const float* __restrict__ encW2,
    const float* __restrict__ muW,   const float* __restrict__ vW,
    const float* __restrict__ decW1, const float* __restrict__ decb1,
    const float* __restrict__ decW2,
    const float* __restrict__ decW3, unsigned int* __restrict__ prep)
{
    __shared__ int hist[NBKT];
    int t = threadIdx.x;

    // zero slice: 512 int4 per block (391*512 = 200192 >= 200000)
    {
        int zi = blockIdx.x * 512 + t;
        if (zi < 200000) zbuf[zi] = make_int4(0, 0, 0, 0);
        zi += 256;
        if (zi < 200000) zbuf[zi] = make_int4(0, 0, 0, 0);
    }

    if (t < NBKT) hist[t] = 0;
    __syncthreads();
    int base = blockIdx.x * 8192;
#pragma unroll
    for (int k = 0; k < 32; ++k) {
        int e = base + k * 256 + t;
        if (e < EE) atomicAdd(&hist[ei[EE + e] >> 9], 1);
    }
    __syncthreads();
    if (t < NBKT) H[t * NBH + blockIdx.x] = hist[t];

    // weight prepack tail (block 0, threads 0-127; no barriers below)
    if (blockIdx.x == 0 && t < 128) {
        int v = t >> 6, l = t & 63;
        int j = l & 31, h = l >> 5;
        const float* W1 = v ? decW1 : encW1;
        const float* b1 = v ? decb1 : encb1;
        const float* W2 = v ? decW2 : encW2;
        int K1 = v ? 4 : 8;
        unsigned short frag[5][8];
#pragma unroll
        for (int i = 0; i < 8; ++i) {
            unsigned short f0;
            if (h == 0) f0 = (i < K1) ? f2bf_fast(W1[i * 32 + j]) : (unsigned short)0;
            else        f0 = (i == 0) ? f2bf_fast(b1[j]) : (unsigned short)0;
            frag[0][i] = f0;
            int k0 = 8 * h + i, k1 = 16 + 8 * h + i;
            frag[1][i] = f2bf_fast(W2[k0 * 32 + j]);
            frag[2][i] = f2bf_fast(W2[k1 * 32 + j]);
            unsigned short w0 = 0, w1 = 0;
            if (j < 4) {
                if (v == 0) {
                    w0 = (j < 2) ? f2bf_fast(muW[k0 * 2 + j]) : f2bf_fast(vW[k0 * 2 + (j - 2)]);
                    w1 = (j < 2) ? f2bf_fast(muW[k1 * 2 + j]) : f2bf_fast(vW[k1 * 2 + (j - 2)]);
                } else {
                    w0 = f2bf_fast(decW3[k0 * 4 + j]);
                    w1 = f2bf_fast(decW3[k1 * 4 + j]);
                }
            }
            frag[3][i] = w0; frag[4][i] = w1;
        }
        uint4* fp = (uint4*)prep;
#pragma unroll
        for (int f = 0; f < 5; ++f) {
            uint4 wds;
            wds.x = (unsigned)frag[f][0] | ((unsigned)frag[f][1] << 16);
            wds.y = (unsigned)frag[f][2] | ((unsigned)frag[f][3] << 16);
            wds.z = (unsigned)frag[f][4] | ((unsigned)frag[f][5] << 16);
            wds.w = (unsigned)frag[f][6] | ((unsigned)frag[f][7] << 16);
            fp[(v * 5 + f) * 64 + l] = wds;
        }
    }
}

// ---- parallel 3-kernel scan over H[NTOT] (proven in rounds 10-14) ----
__global__ __launch_bounds__(256) void spart(
    const int* __restrict__ H, int n, int* __restrict__ part)
{
    int t = threadIdx.x;
    int base = blockIdx.x * 2048 + t * 8;
    int s = 0;
#pragma unroll
    for (int k = 0; k < 8; ++k) { int i = base + k; if (i < n) s += H[i]; }
    __shared__ int red[256];
    red[t] = s;
    __syncthreads();
    for (int d = 128; d > 0; d >>= 1) {
        if (t < d) red[t] += red[t + d];
        __syncthreads();
    }
    if (t == 0) part[blockIdx.x] = red[0];
}

__global__ __launch_bounds__(256) void spscan(int* __restrict__ part, int np)
{
    __shared__ int sa[256], sbuf[256];
    int t = threadIdx.x;
    int v = (t < np) ? part[t] : 0;
    int *pa = sa, *pb = sbuf;
    pa[t] = v;
    __syncthreads();
    for (int d = 1; d < 256; d <<= 1) {
        pb[t] = pa[t] + ((t >= d) ? pa[t - d] : 0);
        __syncthreads();
        int* tp = pa; pa = pb; pb = tp;
    }
    if (t < np) part[t] = pa[t] - v;   // exclusive
}

__global__ __launch_bounds__(256) void sfinal(
    int* __restrict__ H, int n, const int* __restrict__ part)
{
    int t = threadIdx.x;
    int base = blockIdx.x * 2048 + t * 8;
    int v[8]; int s = 0;
#pragma unroll
    for (int k = 0; k < 8; ++k) { int i = base + k; v[k] = (i < n) ? H[i] : 0; s += v[k]; }
    __shared__ int sa[256], sbuf[256];
    int *pa = sa, *pb = sbuf;
    pa[t] = s;
    __syncthreads();
    for (int d = 1; d < 256; d <<= 1) {
        pb[t] = pa[t] + ((t >= d) ? pa[t - d] : 0);
        __syncthreads();
        int* tp = pa; pa = pb; pb = tp;
    }
    int run = part[blockIdx.x] + pa[t] - s;
#pragma unroll
    for (int k = 0; k < 8; ++k) { int i = base + k; if (i < n) { H[i] = run; run += v[k]; } }
}

// packed tmp2: bits 0-16 = src (<2^17), bits 17-25 = dst & 511
__global__ __launch_bounds__(256) void bscatter(
    const int* __restrict__ ei, const int* __restrict__ S, unsigned* __restrict__ tmp2)
{
    __shared__ int cur[NBKT];
    int t = threadIdx.x;
    if (t < NBKT) cur[t] = S[t * NBH + blockIdx.x];
    __syncthreads();
    int base = blockIdx.x * 8192;
#pragma unroll
    for (int k = 0; k < 32; ++k) {
        int e = base + k * 256 + t;
        if (e < EE) {
            int s = ei[e], d = ei[EE + e];
            int p = atomicAdd(&cur[d >> 9], 1);
            tmp2[p] = ((unsigned)(d & 511) << 17) | (unsigned)s;
        }
    }
}

__global__ __launch_bounds__(1024) void bsort(
    const unsigned* __restrict__ tmp2, const int* __restrict__ S,
    int2* __restrict__ sd2, int* __restrict__ off)
{
    int b = blockIdx.x, t = threadIdx.x;
    int bstart = S[b * NBH];
    int bend = (b < NBKT - 1) ? S[(b + 1) * NBH] : EE;
    __shared__ int hist[512], sa[512], sbuf[512];
    if (t < 512) hist[t] = 0;
    __syncthreads();
    for (int e = bstart + t; e < bend; e += 1024)
        atomicAdd(&hist[(tmp2[e] >> 17) & 511], 1);
    __syncthreads();
    int v = 0;
    if (t < 512) { v = hist[t]; sa[t] = v; }
    __syncthreads();
    int *pa = sa, *pb = sbuf;
    for (int d = 1; d < 512; d <<= 1) {
        if (t < 512) pb[t] = pa[t] + ((t >= d) ? pa[t - d] : 0);
        __syncthreads();
        int* tp = pa; pa = pb; pb = tp;
    }
    if (t < 512) {
        int base = bstart + pa[t] - v;   // exclusive
        int n = b * 512 + t;
        if (n < NN) off[n] = base;
        hist[t] = base;                  // cursor
    }
    if (b == 0 && t == 0) off[NN] = EE;
    __syncthreads();
    for (int e = bstart + t; e < bend; e += 1024) {
        unsigned ed = tmp2[e];
        int bin = (int)((ed >> 17) & 511);
        int p = atomicAdd(&hist[bin], 1);
        sd2[p] = make_int2((int)(ed & 0x1FFFFu), (b << 9) | bin);
    }
}

// ================= fallback CSR build (round-6, proven) =================

__global__ __launch_bounds__(256) void rank_kernel(
    const int* __restrict__ ei, int* __restrict__ cnt, unsigned char* __restrict__ tmp)
{
    int e = blockIdx.x * 256 + threadIdx.x;
    int d = ei[EE + e];
    tmp[e] = (unsigned char)atomicAdd(&cnt[d], 1);
}

__global__ __launch_bounds__(256) void partial_kernel(
    const int* __restrict__ cnt, int* __restrict__ partials)
{
    int i0 = blockIdx.x * 1024 + threadIdx.x * 4;
    int s = 0;
    if (i0 + 3 < NN) {
        int4 v = *(const int4*)(cnt + i0);
        s = v.x + v.y + v.z + v.w;
    } else {
        for (int i = i0; i < NN; ++i) s += cnt[i];
    }
#pragma unroll
    for (int d = 1; d < 64; d <<= 1) s += __shfl_xor(s, d);
    __shared__ int ws_[4];
    if ((threadIdx.x & 63) == 0) ws_[threadIdx.x >> 6] = s;
    __syncthreads();
    if (threadIdx.x == 0) partials[blockIdx.x] = ws_[0] + ws_[1] + ws_[2] + ws_[3];
}

__global__ __launch_bounds__(128) void scan_partials(
    int* __restrict__ partials, int* __restrict__ off)
{
    __shared__ int ls[128];
    int t = threadIdx.x;
    int v = (t < 98) ? partials[t] : 0;
    ls[t] = v;
    __syncthreads();
#pragma unroll
    for (int d = 1; d < 128; d <<= 1) {
        int u = (t >= d) ? ls[t - d] : 0;
        __syncthreads();
        ls[t] += u;
        __syncthreads();
    }
    if (t < 98) partials[t] = ls[t] - v;
    if (t == 127) off[NN] = ls[127];
}

__global__ __launch_bounds__(256) void final_scan(
    const int* __restrict__ cnt, const int* __restrict__ partials, int* __restrict__ off)
{
    int t = threadIdx.x;
    int i0 = blockIdx.x * 1024 + t * 4;
    int4 v = {0, 0, 0, 0};
    if (i0 + 3 < NN) {
        v = *(const int4*)(cnt + i0);
    } else {
        int tv[4] = {0, 0, 0, 0};
        for (int k = 0; k < 4 && i0 + k < NN; ++k) tv[k] = cnt[i0 + k];
        v.x = tv[0]; v.y = tv[1]; v.z = tv[2]; v.w = tv[3];
    }
    int s = v.x + v.y + v.z + v.w;
    __shared__ int ls[256];
    ls[t] = s;
    __syncthreads();
#pragma unroll
    for (int d = 1; d < 256; d <<= 1) {
        int u = (t >= d) ? ls[t - d] : 0;
        __syncthreads();
        ls[t] += u;
        __syncthreads();
    }
    int base = partials[blockIdx.x] + ls[t] - s;
    int4 o;
    o.x = base; o.y = base + v.x; o.z = o.y + v.y; o.w = o.z + v.z;
    if (i0 + 3 < NN) {
        *(int4*)(off + i0) = o;
    } else {
        int oo[4] = {o.x, o.y, o.z, o.w};
        for (int k = 0; k < 4 && i0 + k < NN; ++k) off[i0 + k] = oo[k];
    }
}

__global__ __launch_bounds__(256) void place_kernel(
    const int* __restrict__ ei, const int* __restrict__ off,
    const unsigned char* __restrict__ tmp, int2* __restrict__ sd2)
{
    int e = blockIdx.x * 256 + threadIdx.x;
    int s = ei[e], d = ei[EE + e];
    int p = off[d] + (int)tmp[e];
    sd2[p] = make_int2(s, d);
}

// ================= edge MLP: swapped-operand MFMA, in-register transposes =================
// 4 waves/block, each wave processes 128 CSR-consecutive edges (2 x 64-edge pairs).
// __launch_bounds__(256,4): VGPR cap 128 so f32x16 temps stay in VGPRs (no AGPR shuffle).
__global__ __launch_bounds__(256, 4) void edge_mfma(
    const float* __restrict__ feat, int fdim,
    const uint4* __restrict__ wfrag, const float* __restrict__ b2,
    const int2* __restrict__ sd2,
    float* __restrict__ agg4)
{
    __shared__ int   sd[4][128];
    __shared__ float sm4[4][128][5];
    int t = threadIdx.x;
    int w = t >> 6, l = t & 63;
    int h = l >> 5;
    int ebase = (blockIdx.x * 4 + w) * 128;

    // prepacked A fragments (wave-invariant)
    bf16x8 A1  = __builtin_bit_cast(bf16x8, wfrag[l]);
    bf16x8 A2a = __builtin_bit_cast(bf16x8, wfrag[64 + l]);
    bf16x8 A2b = __builtin_bit_cast(bf16x8, wfrag[128 + l]);
    bf16x8 A3a = __builtin_bit_cast(bf16x8, wfrag[192 + l]);
    bf16x8 A3b = __builtin_bit_cast(bf16x8, wfrag[256 + l]);

    // layer-2 bias as MFMA C-in: reg r -> b2[(r&3)+8*(r>>2)+4h]
    f32x16 cb;
    {
        float4 q0 = *(const float4*)(b2 + 4 * h);
        float4 q1 = *(const float4*)(b2 + 8 + 4 * h);
        float4 q2 = *(const float4*)(b2 + 16 + 4 * h);
        float4 q3 = *(const float4*)(b2 + 24 + 4 * h);
        cb[0] = q0.x; cb[1] = q0.y; cb[2] = q0.z; cb[3] = q0.w;
        cb[4] = q1.x; cb[5] = q1.y; cb[6] = q1.z; cb[7] = q1.w;
        cb[8] = q2.x; cb[9] = q2.y; cb[10] = q2.z; cb[11] = q2.w;
        cb[12] = q3.x; cb[13] = q3.y; cb[14] = q3.z; cb[15] = q3.w;
    }

    f32x16 czero = {0.f,0.f,0.f,0.f,0.f,0.f,0.f,0.f,0.f,0.f,0.f,0.f,0.f,0.f,0.f,0.f};

    auto tile = [&](const f32x16& D1, float& o0, float& o1, float& o2, float& o3) {
        unsigned c0 = cvtpk(fmaxf(D1[0], 0.f),  fmaxf(D1[1], 0.f));
        unsigned c1 = cvtpk(fmaxf(D1[2], 0.f),  fmaxf(D1[3], 0.f));
        unsigned c2 = cvtpk(fmaxf(D1[4], 0.f),  fmaxf(D1[5], 0.f));
        unsigned c3 = cvtpk(fmaxf(D1[6], 0.f),  fmaxf(D1[7], 0.f));
        unsigned c4 = cvtpk(fmaxf(D1[8], 0.f),  fmaxf(D1[9], 0.f));
        unsigned c5 = cvtpk(fmaxf(D1[10], 0.f), fmaxf(D1[11], 0.f));
        unsigned c6 = cvtpk(fmaxf(D1[12], 0.f), fmaxf(D1[13], 0.f));
        unsigned c7 = cvtpk(fmaxf(D1[14], 0.f), fmaxf(D1[15], 0.f));
        pl32swap(c0, c2); pl32swap(c1, c3); pl32swap(c4, c6); pl32swap(c5, c7);
        bf16x8 B2a = __builtin_bit_cast(bf16x8, make_uint4(c0, c1, c2, c3));
        bf16x8 B2b = __builtin_bit_cast(bf16x8, make_uint4(c4, c5, c6, c7));
        f32x16 acc = cb;
        acc = __builtin_amdgcn_mfma_f32_32x32x16_bf16(A2a, B2a, acc, 0, 0, 0);
        acc = __builtin_amdgcn_mfma_f32_32x32x16_bf16(A2b, B2b, acc, 0, 0, 0);
        unsigned d0 = cvtpk(fmaxf(acc[0], 0.f),  fmaxf(acc[1], 0.f));
        unsigned d1 = cvtpk(fmaxf(acc[2], 0.f),  fmaxf(acc[3], 0.f));
        unsigned d2 = cvtpk(fmaxf(acc[4], 0.f),  fmaxf(acc[5], 0.f));
        unsigned d3 = cvtpk(fmaxf(acc[6], 0.f),  fmaxf(acc[7], 0.f));
        unsigned d4 = cvtpk(fmaxf(acc[8], 0.f),  fmaxf(acc[9], 0.f));
        unsigned d5 = cvtpk(fmaxf(acc[10], 0.f), fmaxf(acc[11], 0.f));
        unsigned d6 = cvtpk(fmaxf(acc[12], 0.f), fmaxf(acc[13], 0.f));
        unsigned d7 = cvtpk(fmaxf(acc[14], 0.f), fmaxf(acc[15], 0.f));
        pl32swap(d0, d2); pl32swap(d1, d3); pl32swap(d4, d6); pl32swap(d5, d7);
        bf16x8 B3a = __builtin_bit_cast(bf16x8, make_uint4(d0, d1, d2, d3));
        bf16x8 B3b = __builtin_bit_cast(bf16x8, make_uint4(d4, d5, d6, d7));
        f32x16 D3 = czero;
        D3 = __builtin_amdgcn_mfma_f32_32x32x16_bf16(A3a, B3a, D3, 0, 0, 0);
        D3 = __builtin_amdgcn_mfma_f32_32x32x16_bf16(A3b, B3b, D3, 0, 0, 0);
        o0 = D3[0]; o1 = D3[1]; o2 = D3[2]; o3 = D3[3];
    };

#pragma unroll
    for (int p = 0; p < 2; ++p) {
        int eb = ebase + 64 * p;
        int2 me = sd2[eb + l];
        sd[w][64 * p + l] = me.y;

        unsigned F0 = 0, F1 = 0, F2 = 0, F3 = 0;
        if (fdim == 4) {
            float4 xd = *(const float4*)(feat + 4 * me.y);
            float4 xs = *(const float4*)(feat + 4 * me.x);
            F0 = cvtpk(xd.x, xd.y);
            F1 = cvtpk(xd.z, xd.w);
            F2 = cvtpk(xs.x - xd.x, xs.y - xd.y);
            F3 = cvtpk(xs.z - xd.z, xs.w - xd.w);
        } else {
            float2 zd = *(const float2*)(feat + 2 * me.y);
            float2 zs = *(const float2*)(feat + 2 * me.x);
            F0 = cvtpk(zd.x, zd.y);
            F1 = cvtpk(zs.x - zd.x, zs.y - zd.y);
        }
        unsigned G0 = 0x00003F80u, G1 = 0, G2 = 0, G3 = 0;
        pl32swap(F0, G0);
        pl32swap(F1, G1);
        pl32swap(F2, G2);
        pl32swap(F3, G3);
        bf16x8 B1a = __builtin_bit_cast(bf16x8, make_uint4(F0, F1, F2, F3));
        bf16x8 B1b = __builtin_bit_cast(bf16x8, make_uint4(G0, G1, G2, G3));

        float o0, o1, o2, o3;
        f32x16 D1a = __builtin_amdgcn_mfma_f32_32x32x16_bf16(A1, B1a, czero, 0, 0, 0);
        tile(D1a, o0, o1, o2, o3);
        if (h == 0) {
            sm4[w][64 * p + l][0] = o0; sm4[w][64 * p + l][1] = o1;
            sm4[w][64 * p + l][2] = o2; sm4[w][64 * p + l][3] = o3;
        }
        f32x16 D1b = __builtin_amdgcn_mfma_f32_32x32x16_bf16(A1, B1b, czero, 0, 0, 0);
        tile(D1b, o0, o1, o2, o3);
        if (h == 0) {
            sm4[w][64 * p + 32 + l][0] = o0; sm4[w][64 * p + 32 + l][1] = o1;
            sm4[w][64 * p + 32 + l][2] = o2; sm4[w][64 * p + 32 + l][3] = o3;
        }
    }

    // wave-local LDS: intra-wave DS ordering; stop compiler reordering
    asm volatile("" ::: "memory");

    // flush: lane l handles channel c = l&3 over edges [8*seg, 8*seg+8)
    int c = l & 3, e0 = (l >> 2) * 8;
    int cur = sd[w][e0];
    float acc4 = 0.f;
#pragma unroll
    for (int k = 0; k < 8; ++k) {
        int dr = sd[w][e0 + k];
        if (dr != cur) { atomicAdd(&agg4[cur * 4 + c], acc4); acc4 = 0.f; cur = dr; }
        acc4 += sm4[w][e0 + k][c];
    }
    atomicAdd(&agg4[cur * 4 + c], acc4);
}

__global__ __launch_bounds__(256) void node_kernel(
    const float* __restrict__ h4, const int* __restrict__ off,
    const float* __restrict__ eps,
    const float* __restrict__ mub, const float* __restrict__ vb,
    float* __restrict__ z, float* __restrict__ out)
{
    int n = blockIdx.x * 256 + threadIdx.x;
    if (n >= NN) return;
    float inv = 1.f / fmaxf((float)(off[n + 1] - off[n]), 1.f);
    float4 a = *(const float4*)(h4 + 4 * n);
    float mu0 = a.x * inv + mub[0], mu1 = a.y * inv + mub[1];
    float lv0 = a.z * inv + vb[0],  lv1 = a.w * inv + vb[1];
    out[4 * NN + 2 * n]     = mu0;
    out[4 * NN + 2 * n + 1] = mu1;
    out[6 * NN + 2 * n]     = lv0;
    out[6 * NN + 2 * n + 1] = lv1;
    float2 zz;
    zz.x = mu0 + eps[2 * n]     * expf(0.5f * lv0);
    zz.y = mu1 + eps[2 * n + 1] * expf(0.5f * lv1);
    *(float2*)(z + 2 * n) = zz;
}

__global__ __launch_bounds__(256) void final_kernel(
    const float* __restrict__ o4, const int* __restrict__ off,
    const float* __restrict__ b3, float* __restrict__ out)
{
    int n = blockIdx.x * 256 + threadIdx.x;
    if (n >= NN) return;
    float inv = 1.f / fmaxf((float)(off[n + 1] - off[n]), 1.f);
    float4 a = *(const float4*)(o4 + 4 * n);
    float4 r;
    r.x = a.x * inv + b3[0]; r.y = a.y * inv + b3[1];
    r.z = a.z * inv + b3[2]; r.w = a.w * inv + b3[3];
    *(float4*)(out + 4 * n) = r;
}

extern "C" void kernel_launch(void* const* d_in, const int* in_sizes, int n_in,
                              void* d_out, int out_size, void* d_ws, size_t ws_size,
                              hipStream_t stream)
{
    const float* x     = (const float*)d_in[0];
    const int*   ei    = (const int*)d_in[1];
    const float* eps   = (const float*)d_in[2];
    const float* encW1 = (const float*)d_in[3];
    const float* encb1 = (const float*)d_in[4];
    const float* encW2 = (const float*)d_in[5];
    const float* encb2 = (const float*)d_in[6];
    const float* muW   = (const float*)d_in[7];
    const float* mub   = (const float*)d_in[8];
    const float* vW    = (const float*)d_in[9];
    const float* vb    = (const float*)d_in[10];
    const float* decW1 = (const float*)d_in[11];
    const float* decb1 = (const float*)d_in[12];
    const float* decW2 = (const float*)d_in[13];
    const float* decb2 = (const float*)d_in[14];
    const float* decW3 = (const float*)d_in[15];
    const float* decb3 = (const float*)d_in[16];

    int*   wsI = (int*)d_ws;
    float* wsF = (float*)d_ws;
    dim3 blk(256);
    dim3 egrid(6250);                 // 6250 * 4 waves * 128 edges = EE
    dim3 ngrid((NN + 255) / 256);

    int2* sd2; int* off; float* h4; float* out4; float* z; unsigned int* prep;

    if (ws_size >= NEED_FAST) {
        // -------- fast path: LDS-privatized two-level bucket sort (10 dispatches) --------
        sd2  = (int2*)(wsI + WS_SD2F);
        unsigned* tmp2 = (unsigned*)(wsI + WS_TMP2);
        off  = wsI + WS_OFFF;
        int* H    = wsI + WS_H;
        int* part = wsI + WS_PARTF;
        h4   = wsF + WS_H4F;
        out4 = wsF + WS_OUT4F;
        z    = wsF + WS_ZF;
        prep = (unsigned int*)(wsI + WS_PREP);

        bhist_fused<<<dim3(NBH), blk, 0, stream>>>(
            ei, H, (int4*)(wsF + WS_H4F),
            encW1, encb1, encW2, muW, vW,
            decW1, decb1, decW2, decW3, prep);
        spart<<<dim3(NSB), blk, 0, stream>>>(H, NTOT, part);
        spscan<<<dim3(1), blk, 0, stream>>>(part, NSB);
        sfinal<<<dim3(NSB), blk, 0, stream>>>(H, NTOT, part);
        bscatter<<<dim3(NBH), blk, 0, stream>>>(ei, H, tmp2);
        bsort<<<dim3(NBKT), dim3(1024), 0, stream>>>(tmp2, H, sd2, off);
    } else {
        // -------- fallback: round-6 build (global-atomic rank) --------
        sd2  = (int2*)(wsI + FB_SD2);
        off  = wsI + FB_OFF;
        int* cnt  = wsI + FB_CNT;
        int* part = wsI + FB_PART;
        unsigned char* tmp = (unsigned char*)(wsI + FB_TMP);
        h4   = wsF + FB_H4;
        out4 = wsF + FB_OUT4;
        z    = wsF + FB_Z;
        prep = (unsigned int*)(wsI + FB_PREP);

        zero_kernel<<<dim3(98), blk, 0, stream>>>((int4*)(wsI + FB_CNT), 25000);
        wprep_kernel<<<dim3(1), dim3(128), 0, stream>>>(
            encW1, encb1, encW2, muW, vW,
            decW1, decb1, decW2, decW3, prep);
        rank_kernel<<<dim3(12500), blk, 0, stream>>>(ei, cnt, tmp);
        partial_kernel<<<dim3(98), blk, 0, stream>>>(cnt, part);
        scan_partials<<<dim3(1), dim3(128), 0, stream>>>(part, off);
        final_scan<<<dim3(98), blk, 0, stream>>>(cnt, part, off);
        place_kernel<<<dim3(12500), blk, 0, stream>>>(ei, off, tmp, sd2);
        zero_kernel<<<dim3(782), blk, 0, stream>>>((int4*)(wsF + FB_H4), 200000);
    }

    const uint4* wf = (const uint4*)prep;

    edge_mfma<<<egrid, blk, 0, stream>>>(x, 4, wf, encb2, sd2, h4);
    node_kernel<<<ngrid, blk, 0, stream>>>(h4, off, eps, mub, vb, z, (float*)d_out);
    edge_mfma<<<egrid, blk, 0, stream>>>(z, 2, wf + 5 * 64, decb2, sd2, out4);
    final_kernel<<<ngrid, blk, 0, stream>>>(out4, off, decb3, (float*)d_out);
}